// Round 10
// baseline (46.394 us; speedup 1.0000x reference)
//
#include <hip/hip_runtime.h>
#include <math.h>

// st_VQEmbedding via MFMA, wave-decoupled K-split.
// z [65536,64] f32, emb [512,64] f32 -> out = emb[argmin_k (x2-2dot)+e2],
// straight-through (q+x)-x. dot via bf16 2-term split MFMA (al*bh + ah*bl +
// ah*bh, fp32 accum) -- bit-identical chains/term order/tie-break to R5/R7/R8
// (all passed absmax 0.0).
//
// R10: R9's counted s_waitcnt vmcnt(4) raced -- the count breaks if the
// compiler emits ANY extra vmem op (scratch spill/fill, rematerialized
// load) inside the loop. New discipline, robust to arbitrary codegen:
//   per iter: ds_read chunk c -> regs, THEN issue stage(c+1) (other buf),
//   THEN MFMA+dist, THEN s_waitcnt vmcnt(0)+sched_barrier.
// vmcnt(0) waits for everything, so no counting assumption. DMA overlaps
// the MFMA/dist block; 4 blocks/CU (16 waves/CU) hides the remainder.

constexpr int K     = 512;
constexpr int D     = 64;
constexpr int NPTS  = 16 * 4096;   // 65536
constexpr int BLOCK = 256;
constexpr int PPB   = 32;          // points per block (2 16-pt tiles)
constexpr int CHUNK = 16;          // codes per chunk = one MFMA code-tile
constexpr int NCH   = 8;           // chunks per wave (128 codes)

typedef __attribute__((ext_vector_type(8))) short  short8;
typedef __attribute__((ext_vector_type(4))) float  f32x4;

#define AS_G (const __attribute__((address_space(1))) void*)
#define AS_L (__attribute__((address_space(3))) void*)

__device__ inline unsigned short bf16_rne(float f) {
    unsigned u = __builtin_bit_cast(unsigned, f);
    u += 0x7fffu + ((u >> 16) & 1u);
    return (unsigned short)(u >> 16);
}
__device__ inline float bf16_f32(unsigned short h) {
    unsigned u = (unsigned)h << 16;
    return __builtin_bit_cast(float, u);
}

// ---- prep: one thread per code. e2 (exact chain) + bf16 hi/lo split,
// written in LDS-image order: granule g = k*8 + (s ^ (k&7)). ----
__global__ void prep_emb(const float* __restrict__ emb,
                         float* __restrict__ e2,
                         short8* __restrict__ wsHi,
                         short8* __restrict__ wsLo)
{
    const int k = blockIdx.x * 128 + threadIdx.x;   // 4 blocks x 128 = 512
    const float4* row = reinterpret_cast<const float4*>(emb + k * D);
    float v[64];
    #pragma unroll
    for (int i = 0; i < 16; ++i) {
        float4 q = row[i];
        v[4*i+0] = q.x; v[4*i+1] = q.y; v[4*i+2] = q.z; v[4*i+3] = q.w;
    }
    float acc = 0.0f;
    {
        #pragma clang fp contract(off)
        #pragma unroll
        for (int d = 0; d < 64; ++d) acc = acc + v[d] * v[d];
    }
    e2[k] = acc;
    #pragma unroll
    for (int s = 0; s < 8; ++s) {
        short8 hi, lo;
        #pragma unroll
        for (int e = 0; e < 8; ++e) {
            const float f = v[s * 8 + e];
            const unsigned short h = bf16_rne(f);
            const float r = f - bf16_f32(h);      // exact (Sterbenz)
            hi[e] = (short)h;
            lo[e] = (short)bf16_rne(r);
        }
        const int g = k * 8 + (s ^ (k & 7));
        wsHi[g] = hi;
        wsLo[g] = lo;
    }
}

// ---- main: wave-decoupled MFMA argmin + gather -----------------------------
__global__ __launch_bounds__(BLOCK, 4)
void vq_mfma(const float* __restrict__ z,
             const float* __restrict__ emb,
             const float* __restrict__ e2,
             const short8* __restrict__ wsHi,
             const short8* __restrict__ wsLo,
             float* __restrict__ out)
{
    // Per-wave private double buffers: [wave][buf][hi 128 | lo 128] granules.
    __shared__ short8 Abuf[4][2][256];   // 32 KiB
    __shared__ float4 e2L[K / 4];        // 2 KiB
    __shared__ float  bestw[4][PPB];
    __shared__ int    bidxw[4][PPB];
    __shared__ int    bfin[PPB];

    const int tid = threadIdx.x;
    const int wq  = __builtin_amdgcn_readfirstlane(tid >> 6);  // wave id 0..3
    const int l   = tid & 63;
    const int col = l & 15;              // point-in-tile / code-in-tile
    const int kg  = (l >> 4) & 3;        // k-group / code-row group

    const float4* zf4 = reinterpret_cast<const float4*>(z);
    const float4* ef4 = reinterpret_cast<const float4*>(emb);
    float4*       of4 = reinterpret_cast<float4*>(out);

    const int base = blockIdx.x * PPB;

    // stage chunk c of this wave's K-quarter into its private buffer b.
    // Source image is pre-swizzled -> pure lane-linear copy (4 gload_lds).
    auto stage = [&](int c, int b) {
        const int gofs = (wq * 128 + c * CHUNK) * 8;
        #pragma unroll
        for (int i = 0; i < 2; ++i) {
            const int g = i * 64 + l;
            __builtin_amdgcn_global_load_lds(AS_G(wsHi + gofs + g),
                                             AS_L(&Abuf[wq][b][g]), 16, 0, 0);
            __builtin_amdgcn_global_load_lds(AS_G(wsLo + gofs + g),
                                             AS_L(&Abuf[wq][b][128 + g]), 16, 0, 0);
        }
    };

    stage(0, 0);
    if (tid < K / 4)   // e2 -> LDS (2 waves, lane-linear 16B)
        __builtin_amdgcn_global_load_lds(AS_G(e2 + tid * 4),
                                         AS_L(&e2L[tid]), 16, 0, 0);

    // ---- x2, exact sequential unfused chain, ONE point per lane + shfl ----
    const int myp = base + (l & 31);
    float x2c = 0.0f;
    {
        #pragma clang fp contract(off)
        #pragma unroll
        for (int i = 0; i < 16; ++i) {
            float4 q = zf4[myp * 16 + i];
            x2c = x2c + q.x * q.x;
            x2c = x2c + q.y * q.y;
            x2c = x2c + q.z * q.z;
            x2c = x2c + q.w * q.w;
        }
    }
    const float x2v0 = __shfl(x2c, col);        // point base+col
    const float x2v1 = __shfl(x2c, 16 + col);   // point base+16+col

    // ---- B-frags for the 2 point-tiles (identical build to R8) ----
    short8 bh[2][2], bl[2][2];
    #pragma unroll
    for (int p = 0; p < 2; ++p) {
        const int pt = base + p * 16 + col;
        #pragma unroll
        for (int kt = 0; kt < 2; ++kt) {
            const float4 va = zf4[pt * 16 + kt * 8 + kg * 2];
            const float4 vb = zf4[pt * 16 + kt * 8 + kg * 2 + 1];
            const float xs[8] = {va.x, va.y, va.z, va.w, vb.x, vb.y, vb.z, vb.w};
            #pragma unroll
            for (int e = 0; e < 8; ++e) {
                const unsigned short h = bf16_rne(xs[e]);
                const float r = xs[e] - bf16_f32(h);   // exact
                bh[p][kt][e] = (short)h;
                bl[p][kt][e] = (short)bf16_rne(r);
            }
        }
    }

    __syncthreads();   // chunk 0 + e2L staged (barrier drains all vmcnt)

    float best0 = INFINITY, best1 = INFINITY;
    int   bi0 = 0, bi1 = 0;

    #pragma unroll 2
    for (int c = 0; c < NCH; ++c) {
        const int b = c & 1;

        // 1) A-regs for chunk c (its DMA is complete: barrier for c=0,
        //    trailing vmcnt(0) of the previous iteration otherwise).
        const int s0 = col * 8 + (kg ^ (col & 7));
        const short8 ah0 = Abuf[wq][b][s0];
        const short8 ah1 = Abuf[wq][b][s0 ^ 4];
        const short8 al0 = Abuf[wq][b][128 + s0];
        const short8 al1 = Abuf[wq][b][128 + (s0 ^ 4)];

        // 2) prefetch chunk c+1 into the other buffer; overlaps MFMA block
        if (c + 1 < NCH) stage(c + 1, b ^ 1);

        // 3) compute (same term order as R5/R7/R8: {al*bh, ah*bl, ah*bh} x kt)
        f32x4 acc0 = {0.f, 0.f, 0.f, 0.f};
        f32x4 acc1 = {0.f, 0.f, 0.f, 0.f};
        acc0 = __builtin_amdgcn_mfma_f32_16x16x32_bf16(al0, bh[0][0], acc0, 0, 0, 0);
        acc0 = __builtin_amdgcn_mfma_f32_16x16x32_bf16(ah0, bl[0][0], acc0, 0, 0, 0);
        acc0 = __builtin_amdgcn_mfma_f32_16x16x32_bf16(ah0, bh[0][0], acc0, 0, 0, 0);
        acc0 = __builtin_amdgcn_mfma_f32_16x16x32_bf16(al1, bh[0][1], acc0, 0, 0, 0);
        acc0 = __builtin_amdgcn_mfma_f32_16x16x32_bf16(ah1, bl[0][1], acc0, 0, 0, 0);
        acc0 = __builtin_amdgcn_mfma_f32_16x16x32_bf16(ah1, bh[0][1], acc0, 0, 0, 0);

        acc1 = __builtin_amdgcn_mfma_f32_16x16x32_bf16(al0, bh[1][0], acc1, 0, 0, 0);
        acc1 = __builtin_amdgcn_mfma_f32_16x16x32_bf16(ah0, bl[1][0], acc1, 0, 0, 0);
        acc1 = __builtin_amdgcn_mfma_f32_16x16x32_bf16(ah0, bh[1][0], acc1, 0, 0, 0);
        acc1 = __builtin_amdgcn_mfma_f32_16x16x32_bf16(al1, bh[1][1], acc1, 0, 0, 0);
        acc1 = __builtin_amdgcn_mfma_f32_16x16x32_bf16(ah1, bl[1][1], acc1, 0, 0, 0);
        acc1 = __builtin_amdgcn_mfma_f32_16x16x32_bf16(ah1, bh[1][1], acc1, 0, 0, 0);

        const int   klocal = c * CHUNK + kg * 4;
        const int   kglob  = wq * 128 + klocal;
        const float4 e2v   = e2L[(wq * 128 + klocal) >> 2];
        float dt;
        dt = (x2v0 - 2.0f * acc0[0]) + e2v.x; if (dt < best0) { best0 = dt; bi0 = kglob + 0; }
        dt = (x2v0 - 2.0f * acc0[1]) + e2v.y; if (dt < best0) { best0 = dt; bi0 = kglob + 1; }
        dt = (x2v0 - 2.0f * acc0[2]) + e2v.z; if (dt < best0) { best0 = dt; bi0 = kglob + 2; }
        dt = (x2v0 - 2.0f * acc0[3]) + e2v.w; if (dt < best0) { best0 = dt; bi0 = kglob + 3; }
        dt = (x2v1 - 2.0f * acc1[0]) + e2v.x; if (dt < best1) { best1 = dt; bi1 = kglob + 0; }
        dt = (x2v1 - 2.0f * acc1[1]) + e2v.y; if (dt < best1) { best1 = dt; bi1 = kglob + 1; }
        dt = (x2v1 - 2.0f * acc1[2]) + e2v.z; if (dt < best1) { best1 = dt; bi1 = kglob + 2; }
        dt = (x2v1 - 2.0f * acc1[3]) + e2v.w; if (dt < best1) { best1 = dt; bi1 = kglob + 3; }

        // 4) robust drain: waits for chunk c+1's DMA AND any compiler-
        //    emitted vmem (spill/remat) -- no instruction counting.
        if (c + 1 < NCH) {
            asm volatile("s_waitcnt vmcnt(0)" ::: "memory");
            __builtin_amdgcn_sched_barrier(0);
        }
    }

    // combine 4 kg-groups within the wave: lexicographic (dist, idx)
    #pragma unroll
    for (int off = 16; off < 64; off <<= 1) {
        float ov = __shfl_xor(best0, off);
        int   oi = __shfl_xor(bi0,   off);
        if (ov < best0 || (ov == best0 && oi < bi0)) { best0 = ov; bi0 = oi; }
        ov = __shfl_xor(best1, off);
        oi = __shfl_xor(bi1,   off);
        if (ov < best1 || (ov == best1 && oi < bi1)) { best1 = ov; bi1 = oi; }
    }
    if (l < 16) {
        bestw[wq][col]      = best0;  bidxw[wq][col]      = bi0;
        bestw[wq][16 + col] = best1;  bidxw[wq][16 + col] = bi1;
    }
    __syncthreads();

    // combine 4 wave K-quarters: ascending wave = ascending k; strict <
    if (tid < PPB) {
        float bb = bestw[0][tid];
        int   ii = bidxw[0][tid];
        #pragma unroll
        for (int ww = 1; ww < 4; ++ww) {
            const float ob = bestw[ww][tid];
            const int   oi = bidxw[ww][tid];
            if (ob < bb) { bb = ob; ii = oi; }
        }
        bfin[tid] = ii;
    }
    __syncthreads();

    // dense epilogue: lane-linear float4 stores, straight-through (q+x)-x
    #pragma unroll
    for (int i = 0; i < (PPB * 16) / BLOCK; ++i) {   // 2 iters
        const int idx = i * BLOCK + tid;
        const int p   = idx >> 4;
        const int j   = idx & 15;
        const float4 q = ef4[bfin[p] * 16 + j];
        const float4 x = zf4[(base + p) * 16 + j];
        float4 o;
        o.x = (q.x + x.x) - x.x;
        o.y = (q.y + x.y) - x.y;
        o.z = (q.z + x.z) - x.z;
        o.w = (q.w + x.w) - x.w;
        of4[(base + p) * 16 + j] = o;
    }
}

extern "C" void kernel_launch(void* const* d_in, const int* in_sizes, int n_in,
                              void* d_out, int out_size, void* d_ws, size_t ws_size,
                              hipStream_t stream) {
    const float* z   = (const float*)d_in[0];
    const float* emb = (const float*)d_in[1];
    float* out = (float*)d_out;

    // ws: e2 f32[512] (2KB) | wsHi short8[4096] (64KB) | wsLo short8[4096] (64KB)
    float*  e2   = (float*)d_ws;
    short8* wsHi = (short8*)((char*)d_ws + 2048);
    short8* wsLo = (short8*)((char*)d_ws + 2048 + 65536);

    prep_emb<<<4, 128, 0, stream>>>(emb, e2, wsHi, wsLo);
    vq_mfma<<<NPTS / PPB, BLOCK, 0, stream>>>(z, emb, e2, wsHi, wsLo, out);
}